// Round 1
// baseline (2134.385 us; speedup 1.0000x reference)
//
#include <hip/hip_runtime.h>
#include <cstddef>
#include <cstdint>

#define NB 4
#define NH 16
#define SEQ 2048
#define DM 1024
#define DH 64

typedef unsigned short u16;
typedef u16 u16x8 __attribute__((ext_vector_type(8)));
typedef __bf16 b16x8 __attribute__((ext_vector_type(8)));
typedef float f32x4 __attribute__((ext_vector_type(4)));

__device__ inline u16 f2bf(float f) {
  unsigned u = __builtin_bit_cast(unsigned, f);
  u += 0x7fffu + ((u >> 16) & 1u);
  return (u16)(u >> 16);
}

__device__ inline f32x4 zero4() {
  f32x4 z = {0.f, 0.f, 0.f, 0.f};
  return z;
}

// ---- MFMA wrapper: SFINAE hedge on the gfx950 builtin operand type ----
template <typename V>
__device__ inline auto mfma_impl(V a, V b, f32x4 c, int)
    -> decltype(__builtin_amdgcn_mfma_f32_16x16x32_bf16(a, b, c, 0, 0, 0)) {
  return __builtin_amdgcn_mfma_f32_16x16x32_bf16(a, b, c, 0, 0, 0);
}
template <typename V>
__device__ inline f32x4 mfma_impl(V a, V b, f32x4 c, long) {
  typedef short s16x8 __attribute__((ext_vector_type(8)));
  s16x8 as = __builtin_bit_cast(s16x8, a);
  s16x8 bs = __builtin_bit_cast(s16x8, b);
  return __builtin_amdgcn_mfma_f32_16x16x32_bf16(as, bs, c, 0, 0, 0);
}
__device__ inline f32x4 MFMA16(b16x8 a, b16x8 b, f32x4 c) {
  return mfma_impl(a, b, c, 0);
}

// ---- staging load helpers: 8 contiguous elements -> 8 bf16 bits ----
__device__ inline u16x8 ld8(const float* p) {
  f32x4 a = *(const f32x4*)p;
  f32x4 b = *(const f32x4*)(p + 4);
  u16x8 r;
  r[0] = f2bf(a[0]); r[1] = f2bf(a[1]); r[2] = f2bf(a[2]); r[3] = f2bf(a[3]);
  r[4] = f2bf(b[0]); r[5] = f2bf(b[1]); r[6] = f2bf(b[2]); r[7] = f2bf(b[3]);
  return r;
}
__device__ inline u16x8 ld8(const u16* p) { return *(const u16x8*)p; }

// ============================================================
// NT GEMM: C[m][n] = sum_k A[m][k] * W[n][k] + bias[n]
// M = NB*SEQ = 8192, N = K = DM = 1024. 128x128 tile, 4 waves, 4x4 16x16 acc.
// MODE 0: out bf16 [B,H,S,Dh]   (q/k heads)
// MODE 1: out bf16 [B,H,Dh,S]   (v transposed)
// MODE 2: out fp32 [M, DM]      (final projection -> d_out)
// ============================================================
template <int MODE, typename TA>
__global__ __launch_bounds__(256, 2) void gemm_nt(
    const TA* __restrict__ A, const float* __restrict__ W,
    const float* __restrict__ bias, void* __restrict__ out) {
  __shared__ u16 As[128][32];
  __shared__ u16 Bs[128][32];
  const int tid = threadIdx.x;
  const int wave = tid >> 6, lane = tid & 63;
  const int quad = lane >> 4, l16 = lane & 15;
  const int m0 = blockIdx.x * 128, n0 = blockIdx.y * 128;
  const int wm = (wave >> 1) * 64, wn = (wave & 1) * 64;
  const int K = DM;

  f32x4 acc[4][4];
#pragma unroll
  for (int i = 0; i < 4; ++i)
#pragma unroll
    for (int j = 0; j < 4; ++j) acc[i][j] = zero4();

  const int c0 = tid, c1 = 256 + tid;
  const int ar0 = c0 >> 2, ac0 = (c0 & 3) * 8;
  const int ar1 = c1 >> 2, ac1 = (c1 & 3) * 8;

  for (int k0 = 0; k0 < K; k0 += 32) {
    u16x8 a0 = ld8(A + (size_t)(m0 + ar0) * K + k0 + ac0);
    u16x8 a1 = ld8(A + (size_t)(m0 + ar1) * K + k0 + ac1);
    u16x8 b0 = ld8(W + (size_t)(n0 + ar0) * K + k0 + ac0);
    u16x8 b1 = ld8(W + (size_t)(n0 + ar1) * K + k0 + ac1);
    __syncthreads();
    *(u16x8*)&As[ar0][ac0] = a0;
    *(u16x8*)&As[ar1][ac1] = a1;
    *(u16x8*)&Bs[ar0][ac0] = b0;
    *(u16x8*)&Bs[ar1][ac1] = b1;
    __syncthreads();
    b16x8 af[4], bfr[4];
#pragma unroll
    for (int i = 0; i < 4; ++i)
      af[i] = *(const b16x8*)&As[wm + 16 * i + l16][quad * 8];
#pragma unroll
    for (int j = 0; j < 4; ++j)
      bfr[j] = *(const b16x8*)&Bs[wn + 16 * j + l16][quad * 8];
#pragma unroll
    for (int i = 0; i < 4; ++i)
#pragma unroll
      for (int j = 0; j < 4; ++j) acc[i][j] = MFMA16(af[i], bfr[j], acc[i][j]);
  }

#pragma unroll
  for (int i = 0; i < 4; ++i) {
#pragma unroll
    for (int j = 0; j < 4; ++j) {
      const int col = n0 + wn + 16 * j + l16;
      const float bv = bias[col];
#pragma unroll
      for (int r = 0; r < 4; ++r) {
        const int row = m0 + wm + 16 * i + quad * 4 + r;
        const float v = acc[i][j][r] + bv;
        if (MODE == 2) {
          ((float*)out)[(size_t)row * DM + col] = v;
        } else {
          const int b_ = row >> 11, s_ = row & (SEQ - 1);
          const int h_ = col >> 6, d_ = col & (DH - 1);
          size_t idx;
          if (MODE == 0)
            idx = ((size_t)(b_ * NH + h_) * SEQ + s_) * DH + d_;
          else
            idx = ((size_t)(b_ * NH + h_) * DH + d_) * SEQ + s_;
          ((u16*)out)[idx] = f2bf(v);
        }
      }
    }
  }
}

// ============================================================
// Attention: per block = one (b,h) x 64 q-rows. 4 waves, 16 q-rows/wave.
// Pass 1: online (m,l) over k-tiles of 128. Pass 2: recompute scores,
// write normalized p (fp32) to d_out, p->LDS->A-layout, PV accumulate.
// ============================================================
__global__ __launch_bounds__(256, 2) void attn_kernel(
    const u16* __restrict__ qh, const u16* __restrict__ kh,
    const u16* __restrict__ vt, const float* __restrict__ mask,
    float* __restrict__ score_out, u16* __restrict__ attn_out) {
  __shared__ u16 Qs[64][64];
  __shared__ u16 Ks[128][64];
  __shared__ u16 Vs[64][128];
  __shared__ u16 Ps[64][128];

  const int tid = threadIdx.x;
  const int wave = tid >> 6, lane = tid & 63;
  const int quad = lane >> 4, l16 = lane & 15;
  const int bh = blockIdx.x >> 5;  // SEQ/64 = 32 q-tiles per (b,h)
  const int qt = blockIdx.x & 31;
  const int q0 = qt * 64;
  const u16* Q = qh + (size_t)bh * SEQ * DH;
  const u16* Kp = kh + (size_t)bh * SEQ * DH;
  const u16* Vp = vt + (size_t)bh * DH * SEQ;
  float* sout = score_out + (size_t)bh * SEQ * SEQ;
  const int wq = wave * 16;
  const float scale = 0.125f;  // 1/sqrt(64)

  {  // stage Q tile 64x64 (2 chunks of 8 elems per thread)
    int id0 = tid, id1 = 256 + tid;
    int r0 = id0 >> 3, cc0 = (id0 & 7) * 8;
    int r1 = id1 >> 3, cc1 = (id1 & 7) * 8;
    *(u16x8*)&Qs[r0][cc0] = *(const u16x8*)(Q + (size_t)(q0 + r0) * DH + cc0);
    *(u16x8*)&Qs[r1][cc1] = *(const u16x8*)(Q + (size_t)(q0 + r1) * DH + cc1);
  }

  float mrow[4], lrow[4];
#pragma unroll
  for (int r = 0; r < 4; ++r) { mrow[r] = -1e30f; lrow[r] = 0.f; }

  // ---------------- pass 1: row max & sum ----------------
  for (int kt = 0; kt < SEQ; kt += 128) {
    u16x8 kreg[4];
    int krw[4], kcl[4];
#pragma unroll
    for (int c = 0; c < 4; ++c) {
      int id = c * 256 + tid;
      krw[c] = id >> 3;
      kcl[c] = (id & 7) * 8;
      kreg[c] = *(const u16x8*)(Kp + (size_t)(kt + krw[c]) * DH + kcl[c]);
    }
    __syncthreads();
#pragma unroll
    for (int c = 0; c < 4; ++c) *(u16x8*)&Ks[krw[c]][kcl[c]] = kreg[c];
    __syncthreads();

    f32x4 sc[8];
#pragma unroll
    for (int j = 0; j < 8; ++j) sc[j] = zero4();
    b16x8 aq0 = *(const b16x8*)&Qs[wq + l16][quad * 8];
    b16x8 aq1 = *(const b16x8*)&Qs[wq + l16][32 + quad * 8];
#pragma unroll
    for (int j = 0; j < 8; ++j) {
      b16x8 bk0 = *(const b16x8*)&Ks[16 * j + l16][quad * 8];
      b16x8 bk1 = *(const b16x8*)&Ks[16 * j + l16][32 + quad * 8];
      sc[j] = MFMA16(aq0, bk0, sc[j]);
      sc[j] = MFMA16(aq1, bk1, sc[j]);
    }
    float tmax[4] = {-1e30f, -1e30f, -1e30f, -1e30f};
#pragma unroll
    for (int j = 0; j < 8; ++j) {
#pragma unroll
      for (int r = 0; r < 4; ++r) {
        const int grow = q0 + wq + quad * 4 + r;
        const int gcol = kt + 16 * j + l16;
        float v = sc[j][r] * scale + mask[(size_t)grow * SEQ + gcol];
        sc[j][r] = v;
        tmax[r] = fmaxf(tmax[r], v);
      }
    }
#pragma unroll
    for (int r = 0; r < 4; ++r) {
      float t = tmax[r];
      t = fmaxf(t, __shfl_xor(t, 1, 16));
      t = fmaxf(t, __shfl_xor(t, 2, 16));
      t = fmaxf(t, __shfl_xor(t, 4, 16));
      t = fmaxf(t, __shfl_xor(t, 8, 16));
      const float mnew = fmaxf(mrow[r], t);
      float ssum = 0.f;
#pragma unroll
      for (int j = 0; j < 8; ++j) ssum += __expf(sc[j][r] - mnew);
      ssum += __shfl_xor(ssum, 1, 16);
      ssum += __shfl_xor(ssum, 2, 16);
      ssum += __shfl_xor(ssum, 4, 16);
      ssum += __shfl_xor(ssum, 8, 16);
      lrow[r] = lrow[r] * __expf(mrow[r] - mnew) + ssum;
      mrow[r] = mnew;
    }
    __syncthreads();
  }

  float linv[4];
#pragma unroll
  for (int r = 0; r < 4; ++r) linv[r] = 1.f / lrow[r];

  // ---------------- pass 2: write scores + PV ----------------
  f32x4 oacc[4];
#pragma unroll
  for (int dj = 0; dj < 4; ++dj) oacc[dj] = zero4();

  for (int kt = 0; kt < SEQ; kt += 128) {
    u16x8 kreg[4], vreg[4];
    int krw[4], kcl[4], vrw[4], vcl[4];
#pragma unroll
    for (int c = 0; c < 4; ++c) {
      int id = c * 256 + tid;
      krw[c] = id >> 3;
      kcl[c] = (id & 7) * 8;
      kreg[c] = *(const u16x8*)(Kp + (size_t)(kt + krw[c]) * DH + kcl[c]);
      vrw[c] = id >> 4;
      vcl[c] = (id & 15) * 8;
      vreg[c] = *(const u16x8*)(Vp + (size_t)vrw[c] * SEQ + kt + vcl[c]);
    }
    __syncthreads();
#pragma unroll
    for (int c = 0; c < 4; ++c) {
      *(u16x8*)&Ks[krw[c]][kcl[c]] = kreg[c];
      *(u16x8*)&Vs[vrw[c]][vcl[c]] = vreg[c];
    }
    __syncthreads();

    f32x4 sc[8];
#pragma unroll
    for (int j = 0; j < 8; ++j) sc[j] = zero4();
    b16x8 aq0 = *(const b16x8*)&Qs[wq + l16][quad * 8];
    b16x8 aq1 = *(const b16x8*)&Qs[wq + l16][32 + quad * 8];
#pragma unroll
    for (int j = 0; j < 8; ++j) {
      b16x8 bk0 = *(const b16x8*)&Ks[16 * j + l16][quad * 8];
      b16x8 bk1 = *(const b16x8*)&Ks[16 * j + l16][32 + quad * 8];
      sc[j] = MFMA16(aq0, bk0, sc[j]);
      sc[j] = MFMA16(aq1, bk1, sc[j]);
    }
#pragma unroll
    for (int j = 0; j < 8; ++j) {
#pragma unroll
      for (int r = 0; r < 4; ++r) {
        const int grow = q0 + wq + quad * 4 + r;
        const int gcol = kt + 16 * j + l16;
        float v = sc[j][r] * scale + mask[(size_t)grow * SEQ + gcol];
        float p = __expf(v - mrow[r]) * linv[r];
        sout[(size_t)grow * SEQ + gcol] = p;
        Ps[wq + quad * 4 + r][16 * j + l16] = f2bf(p);
      }
    }
    __syncthreads();
#pragma unroll
    for (int kc = 0; kc < 4; ++kc) {
      b16x8 pa = *(const b16x8*)&Ps[wq + l16][kc * 32 + quad * 8];
#pragma unroll
      for (int dj = 0; dj < 4; ++dj) {
        b16x8 vb = *(const b16x8*)&Vs[16 * dj + l16][kc * 32 + quad * 8];
        oacc[dj] = MFMA16(pa, vb, oacc[dj]);
      }
    }
    __syncthreads();
  }

  const int b_ = bh >> 4, h_ = bh & 15;
#pragma unroll
  for (int dj = 0; dj < 4; ++dj) {
#pragma unroll
    for (int r = 0; r < 4; ++r) {
      const int srow = q0 + wq + quad * 4 + r;
      const int d = 16 * dj + l16;
      attn_out[((size_t)(b_ * SEQ + srow)) * DM + h_ * DH + d] =
          f2bf(oacc[dj][r]);
    }
  }
}

// ============================================================
extern "C" void kernel_launch(void* const* d_in, const int* in_sizes, int n_in,
                              void* d_out, int out_size, void* d_ws,
                              size_t ws_size, hipStream_t stream) {
  const float* q = (const float*)d_in[0];
  const float* k = (const float*)d_in[1];
  const float* v = (const float*)d_in[2];
  const float* mask = (const float*)d_in[3];
  const float* w_q = (const float*)d_in[4];
  const float* b_q = (const float*)d_in[5];
  const float* w_k = (const float*)d_in[6];
  const float* b_k = (const float*)d_in[7];
  const float* w_v = (const float*)d_in[8];
  const float* b_v = (const float*)d_in[9];
  const float* w_o = (const float*)d_in[10];
  const float* b_o = (const float*)d_in[11];

  float* out_x = (float*)d_out;
  float* out_score = out_x + (size_t)NB * SEQ * DM;

  const size_t E = (size_t)NB * SEQ * DM;  // 8,388,608 elements
  u16* qh = (u16*)d_ws;
  u16* kh = qh + E;
  u16* vt = kh + E;
  u16* attnb = vt + E;

  dim3 gg(64, 8), bb(256);
  hipLaunchKernelGGL((gemm_nt<0, float>), gg, bb, 0, stream, q, w_q, b_q,
                     (void*)qh);
  hipLaunchKernelGGL((gemm_nt<0, float>), gg, bb, 0, stream, k, w_k, b_k,
                     (void*)kh);
  hipLaunchKernelGGL((gemm_nt<1, float>), gg, bb, 0, stream, v, w_v, b_v,
                     (void*)vt);
  hipLaunchKernelGGL(attn_kernel, dim3(NB * NH * (SEQ / 64)), bb, 0, stream,
                     qh, kh, vt, mask, out_score, attnb);
  hipLaunchKernelGGL((gemm_nt<2, u16>), gg, bb, 0, stream, attnb, w_o, b_o,
                     (void*)out_x);
}